// Round 15
// baseline (365.348 us; speedup 1.0000x reference)
//
#include <hip/hip_runtime.h>
#include <hip/hip_bf16.h>
#include <float.h>

#define Npts 16384
#define Dims 64
#define Oout 128
#define KNN  10
#define LC   12                      // per-stream coarse list
#define NR   16                      // VIRTUAL ranges (8 physical x 2 half-streams)
#define RLEN 2048                    // physical range length
#define NCG  (RLEN / 32)             // 64 cand-groups of 32
#define QW   39                      // queue slots per lane

typedef __attribute__((ext_vector_type(8))) short s16x8;
typedef __attribute__((ext_vector_type(16))) float f32x16;

__device__ __forceinline__ unsigned short f2bf(float f) {
    unsigned u = __float_as_uint(f);
    return (unsigned short)((u + 0x7FFFu + ((u >> 16) & 1u)) >> 16);
}
__device__ __forceinline__ float bf2f(unsigned short b) {
    return __uint_as_float(((unsigned)b) << 16);
}
// bf16 * (-2): flip sign, exp+1 (exact; zero/denorm handled)
__device__ __forceinline__ short neg2(short hs) {
    unsigned short h = (unsigned short)hs;
    unsigned short m = (unsigned short)(h ^ 0x8000u);
    return (short)(((h & 0x7F80u) == 0) ? m : (unsigned short)(m + 0x0080u));
}

__device__ __forceinline__ void insertL(float (&bd)[LC], int (&bi)[LC], float s, int j) {
    if (s < bd[LC - 1]) {
#pragma unroll
        for (int k = LC - 1; k >= 1; --k) {
            bool up = bd[k - 1] > s;
            float nd = up ? bd[k - 1] : ((bd[k] > s) ? s : bd[k]);
            int   ni = up ? bi[k - 1] : ((bd[k] > s) ? j : bi[k]);
            bd[k] = nd; bi[k] = ni;
        }
        bool u0 = bd[0] > s;
        bi[0] = u0 ? j : bi[0];
        bd[0] = u0 ? s : bd[0];
    }
}

// ------- k_tr: transpose + bf16 hi split + sq-aux (bf16 hi/lo) -------
__global__ __launch_bounds__(256) void k_tr(const float* __restrict__ x,
                                            float* __restrict__ ptsT,
                                            unsigned short* __restrict__ xh,
                                            unsigned short* __restrict__ axh) {
    __shared__ float tile[64][65];
    const int b = blockIdx.x;
    for (int i = threadIdx.x; i < 64 * 64; i += 256) {
        int d = i >> 6, p = i & 63;
        tile[d][p] = x[d * Npts + b * 64 + p];
    }
    __syncthreads();
    for (int i = threadIdx.x; i < 64 * 64; i += 256) {
        int p = i >> 6, d = i & 63;
        float v = tile[d][p];
        ptsT[(b * 64 + p) * 64 + d] = v;
        xh[(b * 64 + p) * 64 + d] = (unsigned short)f2bf(v);
    }
    __syncthreads();
    if (threadIdx.x < 64) {
        int p = threadIdx.x;
        float a = 0.f;
#pragma unroll
        for (int d = 0; d < 64; ++d) { float v = tile[d][p]; a = fmaf(v, v, a); }
        unsigned short h = f2bf(a);
        unsigned short lo = f2bf(a - bf2f(h));
        s16x8 v8 = {(short)h, (short)lo, 0, 0, 0, 0, 0, 0};
        *(s16x8*)(axh + (size_t)(b * 64 + p) * 8) = v8;
    }
}

// ------- k_y: y[n][o] = W[o]·pts[n] + b[o], LDS-tiled -------
__global__ __launch_bounds__(256) void k_y(const float* __restrict__ ptsT,
                                           const float* __restrict__ W,
                                           const float* __restrict__ bias,
                                           float* __restrict__ y) {
    __shared__ float wsh[128][65];
    __shared__ float xs[8][64];
    const int t = threadIdx.x;
    const int nb = blockIdx.x * 8;
    for (int i = t; i < 128 * 64; i += 256) {
        int o = i >> 6, d = i & 63;
        wsh[o][d] = W[i];
    }
    for (int i = t; i < 8 * 64; i += 256) {
        int n8 = i >> 6, d = i & 63;
        xs[n8][d] = ptsT[(nb + n8) * 64 + d];
    }
    __syncthreads();
    const int o = t & 127, nn = t >> 7;
    float a0 = bias[o], a1 = a0, a2 = a0, a3 = a0;
#pragma unroll
    for (int d = 0; d < 64; ++d) {
        float wv = wsh[o][d];
        a0 = fmaf(xs[nn * 4 + 0][d], wv, a0);
        a1 = fmaf(xs[nn * 4 + 1][d], wv, a1);
        a2 = fmaf(xs[nn * 4 + 2][d], wv, a2);
        a3 = fmaf(xs[nn * 4 + 3][d], wv, a3);
    }
    y[(nb + nn * 4 + 0) * 128 + o] = a0;
    y[(nb + nn * 4 + 1) * 128 + o] = a1;
    y[(nb + nn * 4 + 2) * 128 + o] = a2;
    y[(nb + nn * 4 + 3) * 128 + o] = a3;
}

// ------- k_knn: 32x32 MFMA; prefetched frags (ping-pong); bank-aligned queues -------
// grid: 512 qgroups x 2 range-pairs; block 256 = 4 waves.
// Wave w: physical range (rp*4+w) of 2048 cands, for the block's 32 queries.
// Swapped mfma: D[cand][query]; lane l -> query l&31, 16 cand-rows
// row = (reg&3) + 8*(reg>>2) + 4*(l>>5)  [m74/m101 layout].
__global__ __launch_bounds__(256, 4) void k_knn(const unsigned short* __restrict__ xh,
                                                const unsigned short* __restrict__ axh,
                                                float* __restrict__ outS,
                                                unsigned short* __restrict__ outI) {
    __shared__ unsigned qq[4][QW][64];     // 39936 B; bank = lane mod 32 (2-way free)

    const int t    = threadIdx.x;
    const int w    = __builtin_amdgcn_readfirstlane(t >> 6);
    const int l    = t & 63;
    const int q31  = l & 31;               // query col (B) AND cand row (A)
    const int hb   = l >> 5;               // half-stream select
    const int hb4  = hb * 4;
    const int qblk = blockIdx.x >> 1;      // 0..511
    const int rp   = blockIdx.x & 1;
    const int range = rp * 4 + w;          // physical 0..7
    const int rbase = range * RLEN;
    const unsigned short* xr  = xh + (size_t)rbase * 64;
    const unsigned short* axr = axh + (size_t)rbase * 8;
    const int q = qblk * 32 + q31;         // lane's own query

    // B-frags: query q, k = s*16 + hb*8 + e, scaled by -2 (exact in bf16)
    s16x8 B0, B1, B2q, B3;
    {
        const unsigned short* qp = xh + (size_t)q * 64 + hb * 8;
        s16x8 h0 = *(const s16x8*)qp;
        s16x8 h1 = *(const s16x8*)(qp + 16);
        s16x8 h2 = *(const s16x8*)(qp + 32);
        s16x8 h3 = *(const s16x8*)(qp + 48);
#pragma unroll
        for (int e = 0; e < 8; ++e) {
            B0[e] = neg2(h0[e]); B1[e] = neg2(h1[e]);
            B2q[e] = neg2(h2[e]); B3[e] = neg2(h3[e]);
        }
    }
    // sq-fold B-frag: B[*][k] = 1.0 for k in {0,1}; k=0..7 live on hb==0 lanes
    s16x8 bs = {0, 0, 0, 0, 0, 0, 0, 0};
    if (hb == 0) { bs[0] = (short)0x3F80; bs[1] = (short)0x3F80; }

    float bd[LC]; int bi[LC];
#pragma unroll
    for (int k = 0; k < LC; ++k) { bd[k] = FLT_MAX; bi[k] = -1; }
    float tau = FLT_MAX;
    int myq = 0;
    unsigned* myqq = &qq[w][0][l];         // slot i at myqq[i*64]

#define LOADG(F0, F1, F2, F3, Fq, gidx)                                          \
    {                                                                            \
        const unsigned short* ap_ = xr + (size_t)((gidx) * 32 + q31) * 64 + hb * 8; \
        F0 = *(const s16x8*)ap_;                                                 \
        F1 = *(const s16x8*)(ap_ + 16);                                          \
        F2 = *(const s16x8*)(ap_ + 32);                                          \
        F3 = *(const s16x8*)(ap_ + 48);                                          \
        Fq = *(const s16x8*)(axr + (size_t)((gidx) * 32 + q31) * 8);             \
    }

#define PROC(F0, F1, F2, F3, Fq, gidx)                                           \
    {                                                                            \
        f32x16 acc = {0.f};                                                      \
        acc = __builtin_amdgcn_mfma_f32_32x32x16_bf16(F0, B0, acc, 0, 0, 0);     \
        acc = __builtin_amdgcn_mfma_f32_32x32x16_bf16(F1, B1, acc, 0, 0, 0);     \
        acc = __builtin_amdgcn_mfma_f32_32x32x16_bf16(F2, B2q, acc, 0, 0, 0);    \
        acc = __builtin_amdgcn_mfma_f32_32x32x16_bf16(F3, B3, acc, 0, 0, 0);     \
        acc = __builtin_amdgcn_mfma_f32_32x32x16_bf16(Fq, bs, acc, 0, 0, 0);     \
        const unsigned pb_ = (unsigned)((gidx) * 16);                            \
        _Pragma("unroll")                                                        \
        for (int r = 0; r < 16; ++r) {                                           \
            const float s_ = acc[r];                                             \
            unsigned e_ = (__float_as_uint(s_) & ~1023u) | (pb_ + r);            \
            myqq[myq * 64] = e_;                                                 \
            myq += (s_ < tau) ? 1 : 0;                                           \
        }                                                                        \
        if (__any(myq > QW - 16)) {                                              \
            for (int i_ = 0; i_ < myq; ++i_) {                                   \
                unsigned e_ = myqq[i_ * 64];                                     \
                int lo_ = (int)(e_ & 1023u);                                     \
                int r_  = lo_ & 15;                                              \
                int c_  = rbase + (lo_ >> 4) * 32 + (r_ & 3) + 8 * (r_ >> 2) + hb4; \
                insertL(bd, bi, __uint_as_float(e_ & ~1023u), c_);               \
            }                                                                    \
            myq = 0;                                                             \
            tau = bd[LC - 1];                                                    \
        }                                                                        \
    }

    // ping-pong: frags for even/odd groups in distinct named registers (no movs)
    s16x8 Pa0, Pa1, Pa2, Pa3, Paq;
    s16x8 Pb0, Pb1, Pb2, Pb3, Pbq;
    LOADG(Pa0, Pa1, Pa2, Pa3, Paq, 0)
    for (int it = 0; it < NCG / 2; ++it) {
        LOADG(Pb0, Pb1, Pb2, Pb3, Pbq, 2 * it + 1)       // prefetch odd group
        PROC (Pa0, Pa1, Pa2, Pa3, Paq, 2 * it)           // compute even group
        LOADG(Pa0, Pa1, Pa2, Pa3, Paq, (2 * it + 2) & 63) // prefetch next even (wraps once, dead)
        PROC (Pb0, Pb1, Pb2, Pb3, Pbq, 2 * it + 1)       // compute odd group
    }
#undef LOADG
#undef PROC

    if (__any(myq != 0)) {
        for (int i = 0; i < myq; ++i) {
            unsigned e = myqq[i * 64];
            int lo = (int)(e & 1023u);
            int r  = lo & 15;
            int c  = rbase + (lo >> 4) * 32 + (r & 3) + 8 * (r >> 2) + hb4;
            insertL(bd, bi, __uint_as_float(e & ~1023u), c);
        }
    }

    // write this (virtual-range, query) sorted top-12
    const int vr = range * 2 + hb;         // 0..15 virtual ranges
    float* os = outS + ((size_t)vr * Npts + q) * LC;
    unsigned short* oi = outI + ((size_t)vr * Npts + q) * LC;
#pragma unroll
    for (int k = 0; k < LC; ++k) {
        os[k] = bd[k];
        oi[k] = (unsigned short)bi[k];
    }
}

// ------- k_out: 2 queries/block; 192 coarse -> top24 -> fp64 top10 -> gather-max -------
__global__ __launch_bounds__(384) void k_out(const float* __restrict__ y,
                                             const float* __restrict__ ptsT,
                                             const float* __restrict__ outS,
                                             const unsigned short* __restrict__ outI,
                                             float* __restrict__ out) {
    __shared__ float  sc[2][NR * LC];
    __shared__ int    ix[2][NR * LC];
    __shared__ float  s2[2][96];
    __shared__ int    i2[2][96];
    __shared__ int    c24[2][24];
    __shared__ double d2s[2][24];
    __shared__ int    cix[2][24];
    __shared__ __align__(16) float qs[2][Dims];
    __shared__ int    nb[2][KNN];

    const int ts = threadIdx.x;
    const int h  = ts / 192;               // which query of the pair
    const int t  = ts - h * 192;
    const int n  = blockIdx.x * 2 + h;

    if (t < Dims) qs[h][t] = ptsT[(size_t)n * Dims + t];
    {
        const int r = t / LC, k = t - r * LC;   // t < 192 = NR*LC
        sc[h][t] = outS[((size_t)r * Npts + n) * LC + k];
        ix[h][t] = (int)outI[((size_t)r * Npts + n) * LC + k];
    }
    __syncthreads();

    // phase 1: rank within group of 48, keep top-24 of each (4 groups -> 96)
    {
        const int gb = (t / 48) * 48;
        const float v = sc[h][t]; const int vi = ix[h][t];
        int rk = 0;
        for (int c = 0; c < 48; ++c) {
            float oc = sc[h][gb + c]; int oi = ix[h][gb + c];
            rk += (oc < v || (oc == v && oi < vi)) ? 1 : 0;
        }
        if (rk < 24) { s2[h][(t / 48) * 24 + rk] = v; i2[h][(t / 48) * 24 + rk] = vi; }
    }
    __syncthreads();

    // phase 2: 96 -> coarse top-24
    if (t < 96) {
        const float v = s2[h][t]; const int vi = i2[h][t];
        int rk = 0;
        for (int c = 0; c < 96; ++c)
            rk += (s2[h][c] < v || (s2[h][c] == v && i2[h][c] < vi)) ? 1 : 0;
        if (rk < 24) c24[h][rk] = vi;
    }
    __syncthreads();

    // exact fp64 d2 for 24 candidates
    if (t < 24) {
        const int j = c24[h][t];
        double acc = 0.0;
#pragma unroll
        for (int d4 = 0; d4 < Dims / 4; ++d4) {
            const float4 pv = *(const float4*)&ptsT[(size_t)j * Dims + d4 * 4];
            const float4 qv = *(const float4*)&qs[h][d4 * 4];
            double e0 = (double)qv.x - (double)pv.x;
            double e1 = (double)qv.y - (double)pv.y;
            double e2 = (double)qv.z - (double)pv.z;
            double e3 = (double)qv.w - (double)pv.w;
            acc = fma(e0, e0, acc); acc = fma(e1, e1, acc);
            acc = fma(e2, e2, acc); acc = fma(e3, e3, acc);
        }
        d2s[h][t] = acc; cix[h][t] = j;
    }
    __syncthreads();

    // exact top-10 by (d2, idx)
    if (t < 24) {
        const double dv = d2s[h][t]; const int ji = cix[h][t];
        int rk = 0;
        for (int c = 0; c < 24; ++c)
            rk += (d2s[h][c] < dv || (d2s[h][c] == dv && cix[h][c] < ji)) ? 1 : 0;
        if (rk < KNN) nb[h][rk] = ji;
    }
    __syncthreads();

    if (t < Oout) {
        float m = -FLT_MAX;
#pragma unroll
        for (int k = 0; k < KNN; ++k)
            m = fmaxf(m, y[(size_t)nb[h][k] * Oout + t]);
        out[(size_t)n * Oout + t] = m;
    }
}

// ---------------- launcher ----------------
extern "C" void kernel_launch(void* const* d_in, const int* in_sizes, int n_in,
                              void* d_out, int out_size, void* d_ws, size_t ws_size,
                              hipStream_t stream) {
    const float* x = (const float*)d_in[0];   // (1, 64, 16384)
    const float* W = (const float*)d_in[1];   // (128, 64)
    const float* b = (const float*)d_in[2];   // (128,)
    float* out = (float*)d_out;

    float* ws   = (float*)d_ws;
    float* ptsT = ws;                                        // N*D          (4 MB)
    float* y    = ptsT + (size_t)Npts * Dims;                // N*O          (8 MB)
    unsigned short* xh  = (unsigned short*)(y + (size_t)Npts * Oout); // N*D bf16 (2 MB)
    unsigned short* axh = xh + (size_t)Npts * Dims;          // N*8 bf16     (256 KB)
    float* outS = (float*)(axh + (size_t)Npts * 8);          // NR*N*LC f32  (12 MB)
    unsigned short* outI = (unsigned short*)(outS + (size_t)NR * Npts * LC); // (6 MB)

    k_tr <<<Npts / 64, 256, 0, stream>>>(x, ptsT, xh, axh);
    k_y  <<<Npts / 8, 256, 0, stream>>>(ptsT, W, b, y);
    k_knn<<<1024, 256, 0, stream>>>(xh, axh, outS, outI);
    k_out<<<Npts / 2, 384, 0, stream>>>(y, ptsT, outS, outI, out);
}

// Round 16
// 280.126 us; speedup vs baseline: 1.3042x; 1.3042x over previous
//
#include <hip/hip_runtime.h>
#include <hip/hip_bf16.h>
#include <float.h>

#define Npts 16384
#define Dims 64
#define Oout 128
#define KNN  10
#define LC   10                      // per-stream coarse list (top-10 suffices)
#define NR   16                      // VIRTUAL ranges (8 physical x 2 half-streams)
#define RLEN 2048                    // physical range length
#define NCG  (RLEN / 32)             // 64 cand-groups of 32
#define QW   39                      // queue slots per lane

typedef __attribute__((ext_vector_type(8))) short s16x8;
typedef __attribute__((ext_vector_type(16))) float f32x16;

__device__ __forceinline__ unsigned short f2bf(float f) {
    unsigned u = __float_as_uint(f);
    return (unsigned short)((u + 0x7FFFu + ((u >> 16) & 1u)) >> 16);
}
__device__ __forceinline__ float bf2f(unsigned short b) {
    return __uint_as_float(((unsigned)b) << 16);
}
// bf16 * (-2): flip sign, exp+1 (exact; zero/denorm handled)
__device__ __forceinline__ short neg2(short hs) {
    unsigned short h = (unsigned short)hs;
    unsigned short m = (unsigned short)(h ^ 0x8000u);
    return (short)(((h & 0x7F80u) == 0) ? m : (unsigned short)(m + 0x0080u));
}

__device__ __forceinline__ void insertL(float (&bd)[LC], int (&bi)[LC], float s, int j) {
    if (s < bd[LC - 1]) {
#pragma unroll
        for (int k = LC - 1; k >= 1; --k) {
            bool up = bd[k - 1] > s;
            float nd = up ? bd[k - 1] : ((bd[k] > s) ? s : bd[k]);
            int   ni = up ? bi[k - 1] : ((bd[k] > s) ? j : bi[k]);
            bd[k] = nd; bi[k] = ni;
        }
        bool u0 = bd[0] > s;
        bi[0] = u0 ? j : bi[0];
        bd[0] = u0 ? s : bd[0];
    }
}

// ------- k_tr: transpose + bf16 hi split + sq-aux (bf16 hi/lo) -------
__global__ __launch_bounds__(256) void k_tr(const float* __restrict__ x,
                                            float* __restrict__ ptsT,
                                            unsigned short* __restrict__ xh,
                                            unsigned short* __restrict__ axh) {
    __shared__ float tile[64][65];
    const int b = blockIdx.x;
    for (int i = threadIdx.x; i < 64 * 64; i += 256) {
        int d = i >> 6, p = i & 63;
        tile[d][p] = x[d * Npts + b * 64 + p];
    }
    __syncthreads();
    for (int i = threadIdx.x; i < 64 * 64; i += 256) {
        int p = i >> 6, d = i & 63;
        float v = tile[d][p];
        ptsT[(b * 64 + p) * 64 + d] = v;
        xh[(b * 64 + p) * 64 + d] = (unsigned short)f2bf(v);
    }
    __syncthreads();
    if (threadIdx.x < 64) {
        int p = threadIdx.x;
        float a = 0.f;
#pragma unroll
        for (int d = 0; d < 64; ++d) { float v = tile[d][p]; a = fmaf(v, v, a); }
        unsigned short h = f2bf(a);
        unsigned short lo = f2bf(a - bf2f(h));
        s16x8 v8 = {(short)h, (short)lo, 0, 0, 0, 0, 0, 0};
        *(s16x8*)(axh + (size_t)(b * 64 + p) * 8) = v8;
    }
}

// ------- k_y: y[n][o] = W[o]·pts[n] + b[o], LDS-tiled -------
__global__ __launch_bounds__(256) void k_y(const float* __restrict__ ptsT,
                                           const float* __restrict__ W,
                                           const float* __restrict__ bias,
                                           float* __restrict__ y) {
    __shared__ float wsh[128][65];
    __shared__ float xs[8][64];
    const int t = threadIdx.x;
    const int nb = blockIdx.x * 8;
    for (int i = t; i < 128 * 64; i += 256) {
        int o = i >> 6, d = i & 63;
        wsh[o][d] = W[i];
    }
    for (int i = t; i < 8 * 64; i += 256) {
        int n8 = i >> 6, d = i & 63;
        xs[n8][d] = ptsT[(nb + n8) * 64 + d];
    }
    __syncthreads();
    const int o = t & 127, nn = t >> 7;
    float a0 = bias[o], a1 = a0, a2 = a0, a3 = a0;
#pragma unroll
    for (int d = 0; d < 64; ++d) {
        float wv = wsh[o][d];
        a0 = fmaf(xs[nn * 4 + 0][d], wv, a0);
        a1 = fmaf(xs[nn * 4 + 1][d], wv, a1);
        a2 = fmaf(xs[nn * 4 + 2][d], wv, a2);
        a3 = fmaf(xs[nn * 4 + 3][d], wv, a3);
    }
    y[(nb + nn * 4 + 0) * 128 + o] = a0;
    y[(nb + nn * 4 + 1) * 128 + o] = a1;
    y[(nb + nn * 4 + 2) * 128 + o] = a2;
    y[(nb + nn * 4 + 3) * 128 + o] = a3;
}

// ------- k_knn: 32x32 MFMA; prefetched frags (ping-pong); bank-aligned queues -------
// grid: 512 qgroups x 2 range-pairs; block 256 = 4 waves.
// Wave w: physical range (rp*4+w) of 2048 cands, for the block's 32 queries.
// Swapped mfma: D[cand][query]; lane l -> query l&31, 16 cand-rows
// row = (reg&3) + 8*(reg>>2) + 4*(l>>5)  [m74/m101 layout].
__global__ __launch_bounds__(256, 4) void k_knn(const unsigned short* __restrict__ xh,
                                                const unsigned short* __restrict__ axh,
                                                float* __restrict__ outS,
                                                unsigned short* __restrict__ outI) {
    __shared__ unsigned qq[4][QW][64];     // 39936 B; bank = lane mod 32 (2-way free)

    const int t    = threadIdx.x;
    const int w    = __builtin_amdgcn_readfirstlane(t >> 6);
    const int l    = t & 63;
    const int q31  = l & 31;               // query col (B) AND cand row (A)
    const int hb   = l >> 5;               // half-stream select
    const int hb4  = hb * 4;
    const int qblk = blockIdx.x >> 1;      // 0..511
    const int rp   = blockIdx.x & 1;
    const int range = rp * 4 + w;          // physical 0..7
    const int rbase = range * RLEN;
    const unsigned short* xr  = xh + (size_t)rbase * 64;
    const unsigned short* axr = axh + (size_t)rbase * 8;
    const int q = qblk * 32 + q31;         // lane's own query

    // B-frags: query q, k = s*16 + hb*8 + e, scaled by -2 (exact in bf16)
    s16x8 B0, B1, B2q, B3;
    {
        const unsigned short* qp = xh + (size_t)q * 64 + hb * 8;
        s16x8 h0 = *(const s16x8*)qp;
        s16x8 h1 = *(const s16x8*)(qp + 16);
        s16x8 h2 = *(const s16x8*)(qp + 32);
        s16x8 h3 = *(const s16x8*)(qp + 48);
#pragma unroll
        for (int e = 0; e < 8; ++e) {
            B0[e] = neg2(h0[e]); B1[e] = neg2(h1[e]);
            B2q[e] = neg2(h2[e]); B3[e] = neg2(h3[e]);
        }
    }
    // sq-fold B-frag: B[*][k] = 1.0 for k in {0,1}; k=0..7 live on hb==0 lanes
    s16x8 bs = {0, 0, 0, 0, 0, 0, 0, 0};
    if (hb == 0) { bs[0] = (short)0x3F80; bs[1] = (short)0x3F80; }

    float bd[LC]; int bi[LC];
#pragma unroll
    for (int k = 0; k < LC; ++k) { bd[k] = FLT_MAX; bi[k] = -1; }
    float tau = FLT_MAX;
    int myq = 0;
    unsigned* myqq = &qq[w][0][l];         // slot i at myqq[i*64]

#define LOADG(F0, F1, F2, F3, Fq, gidx)                                          \
    {                                                                            \
        const unsigned short* ap_ = xr + (size_t)((gidx) * 32 + q31) * 64 + hb * 8; \
        F0 = *(const s16x8*)ap_;                                                 \
        F1 = *(const s16x8*)(ap_ + 16);                                          \
        F2 = *(const s16x8*)(ap_ + 32);                                          \
        F3 = *(const s16x8*)(ap_ + 48);                                          \
        Fq = *(const s16x8*)(axr + (size_t)((gidx) * 32 + q31) * 8);             \
    }

#define PROC(F0, F1, F2, F3, Fq, gidx)                                           \
    {                                                                            \
        f32x16 acc = {0.f};                                                      \
        acc = __builtin_amdgcn_mfma_f32_32x32x16_bf16(F0, B0, acc, 0, 0, 0);     \
        acc = __builtin_amdgcn_mfma_f32_32x32x16_bf16(F1, B1, acc, 0, 0, 0);     \
        acc = __builtin_amdgcn_mfma_f32_32x32x16_bf16(F2, B2q, acc, 0, 0, 0);    \
        acc = __builtin_amdgcn_mfma_f32_32x32x16_bf16(F3, B3, acc, 0, 0, 0);     \
        acc = __builtin_amdgcn_mfma_f32_32x32x16_bf16(Fq, bs, acc, 0, 0, 0);     \
        const unsigned pb_ = (unsigned)((gidx) * 16);                            \
        _Pragma("unroll")                                                        \
        for (int r = 0; r < 16; ++r) {                                           \
            const float s_ = acc[r];                                             \
            unsigned e_ = (__float_as_uint(s_) & ~1023u) | (pb_ + r);            \
            myqq[myq * 64] = e_;                                                 \
            myq += (s_ < tau) ? 1 : 0;                                           \
        }                                                                        \
        if (__any(myq > QW - 16)) {                                              \
            for (int i_ = 0; i_ < myq; ++i_) {                                   \
                unsigned e_ = myqq[i_ * 64];                                     \
                int lo_ = (int)(e_ & 1023u);                                     \
                int r_  = lo_ & 15;                                              \
                int c_  = rbase + (lo_ >> 4) * 32 + (r_ & 3) + 8 * (r_ >> 2) + hb4; \
                insertL(bd, bi, __uint_as_float(e_ & ~1023u), c_);               \
            }                                                                    \
            myq = 0;                                                             \
            tau = bd[LC - 1];                                                    \
        }                                                                        \
    }

    // ping-pong: frags for even/odd groups in distinct named registers (no movs)
    s16x8 Pa0, Pa1, Pa2, Pa3, Paq;
    s16x8 Pb0, Pb1, Pb2, Pb3, Pbq;
    LOADG(Pa0, Pa1, Pa2, Pa3, Paq, 0)
    for (int it = 0; it < NCG / 2; ++it) {
        LOADG(Pb0, Pb1, Pb2, Pb3, Pbq, 2 * it + 1)        // prefetch odd group
        PROC (Pa0, Pa1, Pa2, Pa3, Paq, 2 * it)            // compute even group
        LOADG(Pa0, Pa1, Pa2, Pa3, Paq, (2 * it + 2) & 63) // prefetch next even (wraps once, dead)
        PROC (Pb0, Pb1, Pb2, Pb3, Pbq, 2 * it + 1)        // compute odd group
    }
#undef LOADG
#undef PROC

    if (__any(myq != 0)) {
        for (int i = 0; i < myq; ++i) {
            unsigned e = myqq[i * 64];
            int lo = (int)(e & 1023u);
            int r  = lo & 15;
            int c  = rbase + (lo >> 4) * 32 + (r & 3) + 8 * (r >> 2) + hb4;
            insertL(bd, bi, __uint_as_float(e & ~1023u), c);
        }
    }

    // write this (virtual-range, query) sorted top-10
    const int vr = range * 2 + hb;         // 0..15 virtual ranges
    float* os = outS + ((size_t)vr * Npts + q) * LC;
    unsigned short* oi = outI + ((size_t)vr * Npts + q) * LC;
#pragma unroll
    for (int k = 0; k < LC; ++k) {
        os[k] = bd[k];
        oi[k] = (unsigned short)bi[k];
    }
}

// ------- k_out: 160 coarse -> top24 (2-phase rank) -> fp64 top10 -> gather-max -------
__global__ __launch_bounds__(192) void k_out(const float* __restrict__ y,
                                             const float* __restrict__ ptsT,
                                             const float* __restrict__ outS,
                                             const unsigned short* __restrict__ outI,
                                             float* __restrict__ out) {
    __shared__ float  sc[NR * LC];
    __shared__ int    ix[NR * LC];
    __shared__ float  s2[96];
    __shared__ int    i2[96];
    __shared__ int    c24[24];
    __shared__ double d2s[24];
    __shared__ int    ci[24];
    __shared__ __align__(16) float qs[Dims];
    __shared__ int    nb[KNN];

    const int n = blockIdx.x;
    const int t = threadIdx.x;

    if (t < Dims) qs[t] = ptsT[(size_t)n * Dims + t];
    if (t < NR * LC) {
        const int r = t / LC, k = t - r * LC;   // 160 entries
        sc[t] = outS[((size_t)r * Npts + n) * LC + k];
        ix[t] = (int)outI[((size_t)r * Npts + n) * LC + k];
    }
    __syncthreads();

    // phase 1: rank within group of 40, keep top-24 of each (4 groups -> 96)
    if (t < NR * LC) {
        const int gb = (t / 40) * 40;
        const float v = sc[t]; const int vi = ix[t];
        int rk = 0;
        for (int c = 0; c < 40; ++c) {
            float oc = sc[gb + c]; int oi = ix[gb + c];
            rk += (oc < v || (oc == v && oi < vi)) ? 1 : 0;
        }
        if (rk < 24) { s2[(t / 40) * 24 + rk] = v; i2[(t / 40) * 24 + rk] = vi; }
    }
    __syncthreads();

    // phase 2: 96 -> coarse top-24
    if (t < 96) {
        const float v = s2[t]; const int vi = i2[t];
        int rk = 0;
        for (int c = 0; c < 96; ++c)
            rk += (s2[c] < v || (s2[c] == v && i2[c] < vi)) ? 1 : 0;
        if (rk < 24) c24[rk] = vi;
    }
    __syncthreads();

    // exact fp64 d2 for 24 candidates
    if (t < 24) {
        const int j = c24[t];
        double acc = 0.0;
#pragma unroll
        for (int d4 = 0; d4 < Dims / 4; ++d4) {
            const float4 pv = *(const float4*)&ptsT[(size_t)j * Dims + d4 * 4];
            const float4 qv = *(const float4*)&qs[d4 * 4];
            double e0 = (double)qv.x - (double)pv.x;
            double e1 = (double)qv.y - (double)pv.y;
            double e2 = (double)qv.z - (double)pv.z;
            double e3 = (double)qv.w - (double)pv.w;
            acc = fma(e0, e0, acc); acc = fma(e1, e1, acc);
            acc = fma(e2, e2, acc); acc = fma(e3, e3, acc);
        }
        d2s[t] = acc; ci[t] = j;
    }
    __syncthreads();

    // exact top-10 by (d2, idx)
    if (t < 24) {
        const double dv = d2s[t]; const int ji = ci[t];
        int rk = 0;
        for (int c = 0; c < 24; ++c)
            rk += (d2s[c] < dv || (d2s[c] == dv && ci[c] < ji)) ? 1 : 0;
        if (rk < KNN) nb[rk] = ji;
    }
    __syncthreads();

    if (t < Oout) {
        float m = -FLT_MAX;
#pragma unroll
        for (int k = 0; k < KNN; ++k)
            m = fmaxf(m, y[(size_t)nb[k] * Oout + t]);
        out[(size_t)n * Oout + t] = m;
    }
}

// ---------------- launcher ----------------
extern "C" void kernel_launch(void* const* d_in, const int* in_sizes, int n_in,
                              void* d_out, int out_size, void* d_ws, size_t ws_size,
                              hipStream_t stream) {
    const float* x = (const float*)d_in[0];   // (1, 64, 16384)
    const float* W = (const float*)d_in[1];   // (128, 64)
    const float* b = (const float*)d_in[2];   // (128,)
    float* out = (float*)d_out;

    float* ws   = (float*)d_ws;
    float* ptsT = ws;                                        // N*D          (4 MB)
    float* y    = ptsT + (size_t)Npts * Dims;                // N*O          (8 MB)
    unsigned short* xh  = (unsigned short*)(y + (size_t)Npts * Oout); // N*D bf16 (2 MB)
    unsigned short* axh = xh + (size_t)Npts * Dims;          // N*8 bf16     (256 KB)
    float* outS = (float*)(axh + (size_t)Npts * 8);          // NR*N*LC f32  (10.5 MB)
    unsigned short* outI = (unsigned short*)(outS + (size_t)NR * Npts * LC); // (5.2 MB)

    k_tr <<<Npts / 64, 256, 0, stream>>>(x, ptsT, xh, axh);
    k_y  <<<Npts / 8, 256, 0, stream>>>(ptsT, W, b, y);
    k_knn<<<1024, 256, 0, stream>>>(xh, axh, outS, outI);
    k_out<<<Npts, 192, 0, stream>>>(y, ptsT, outS, outI, out);
}

// Round 17
// 247.276 us; speedup vs baseline: 1.4775x; 1.1328x over previous
//
#include <hip/hip_runtime.h>
#include <hip/hip_bf16.h>
#include <float.h>

#define Npts 16384
#define Dims 64
#define Oout 128
#define KNN  10
#define LC   10                      // per-stream coarse list (top-10)
#define NR   16                      // VIRTUAL ranges (8 physical x 2 half-streams)
#define RLEN 2048                    // physical range length
#define NCG  (RLEN / 32)             // 64 cand-groups of 32
#define QW   39                      // queue slots per lane

typedef __attribute__((ext_vector_type(8))) short s16x8;
typedef __attribute__((ext_vector_type(16))) float f32x16;

__device__ __forceinline__ unsigned short f2bf(float f) {
    unsigned u = __float_as_uint(f);
    return (unsigned short)((u + 0x7FFFu + ((u >> 16) & 1u)) >> 16);
}
__device__ __forceinline__ float bf2f(unsigned short b) {
    return __uint_as_float(((unsigned)b) << 16);
}
// bf16 * (-2): flip sign, exp+1 (exact; zero/denorm handled)
__device__ __forceinline__ short neg2(short hs) {
    unsigned short h = (unsigned short)hs;
    unsigned short m = (unsigned short)(h ^ 0x8000u);
    return (short)(((h & 0x7F80u) == 0) ? m : (unsigned short)(m + 0x0080u));
}

// sorted-ascending uint top-10 insert (3 inst/stage: cmp + umin + cndmask)
__device__ __forceinline__ void insertU(unsigned (&bd)[LC], unsigned e) {
    if (e < bd[LC - 1]) {
#pragma unroll
        for (int k = LC - 1; k >= 1; --k) {
            unsigned mn = (bd[k] < e) ? bd[k] : e;
            bd[k] = (bd[k - 1] > e) ? bd[k - 1] : mn;
        }
        bd[0] = (bd[0] < e) ? bd[0] : e;
    }
}

// ------- k_tr: transpose + bf16 hi split + (sq+256)-aux (bf16 hi/lo) -------
__global__ __launch_bounds__(256) void k_tr(const float* __restrict__ x,
                                            float* __restrict__ ptsT,
                                            unsigned short* __restrict__ xh,
                                            unsigned short* __restrict__ axh) {
    __shared__ float tile[64][65];
    const int b = blockIdx.x;
    for (int i = threadIdx.x; i < 64 * 64; i += 256) {
        int d = i >> 6, p = i & 63;
        tile[d][p] = x[d * Npts + b * 64 + p];
    }
    __syncthreads();
    for (int i = threadIdx.x; i < 64 * 64; i += 256) {
        int p = i >> 6, d = i & 63;
        float v = tile[d][p];
        ptsT[(b * 64 + p) * 64 + d] = v;
        xh[(b * 64 + p) * 64 + d] = (unsigned short)f2bf(v);
    }
    __syncthreads();
    if (threadIdx.x < 64) {
        int p = threadIdx.x;
        float a = 0.f;
#pragma unroll
        for (int d = 0; d < 64; ++d) { float v = tile[d][p]; a = fmaf(v, v, a); }
        a += 256.f;                       // positivity shift: score = d2 - sqq + 256 > 0
        unsigned short h = f2bf(a);
        unsigned short lo = f2bf(a - bf2f(h));
        s16x8 v8 = {(short)h, (short)lo, 0, 0, 0, 0, 0, 0};
        *(s16x8*)(axh + (size_t)(b * 64 + p) * 8) = v8;
    }
}

// ------- k_y: y[n][o] = W[o]·pts[n] + b[o], LDS-tiled -------
__global__ __launch_bounds__(256) void k_y(const float* __restrict__ ptsT,
                                           const float* __restrict__ W,
                                           const float* __restrict__ bias,
                                           float* __restrict__ y) {
    __shared__ float wsh[128][65];
    __shared__ float xs[8][64];
    const int t = threadIdx.x;
    const int nb = blockIdx.x * 8;
    for (int i = t; i < 128 * 64; i += 256) {
        int o = i >> 6, d = i & 63;
        wsh[o][d] = W[i];
    }
    for (int i = t; i < 8 * 64; i += 256) {
        int n8 = i >> 6, d = i & 63;
        xs[n8][d] = ptsT[(nb + n8) * 64 + d];
    }
    __syncthreads();
    const int o = t & 127, nn = t >> 7;
    float a0 = bias[o], a1 = a0, a2 = a0, a3 = a0;
#pragma unroll
    for (int d = 0; d < 64; ++d) {
        float wv = wsh[o][d];
        a0 = fmaf(xs[nn * 4 + 0][d], wv, a0);
        a1 = fmaf(xs[nn * 4 + 1][d], wv, a1);
        a2 = fmaf(xs[nn * 4 + 2][d], wv, a2);
        a3 = fmaf(xs[nn * 4 + 3][d], wv, a3);
    }
    y[(nb + nn * 4 + 0) * 128 + o] = a0;
    y[(nb + nn * 4 + 1) * 128 + o] = a1;
    y[(nb + nn * 4 + 2) * 128 + o] = a2;
    y[(nb + nn * 4 + 3) * 128 + o] = a3;
}

// ------- k_knn: 32x32 MFMA; packed-uint selection; bank-aligned queues -------
// grid: 512 qgroups x 2 range-pairs; block 256 = 4 waves.
// Wave w: physical range (rp*4+w) of 2048 cands, for the block's 32 queries.
// Swapped mfma: D[cand][query]; lane l -> query l&31, 16 cand-rows
// row = (reg&3) + 8*(reg>>2) + 4*(l>>5)  [m74/m101 layout].
// Scores positive (+256 fold) -> IEEE bits monotone as uint; packed
// (bits & ~1023) | local_idx compares lexicographic (score, idx) exactly.
__global__ __launch_bounds__(256, 4) void k_knn(const unsigned short* __restrict__ xh,
                                                const unsigned short* __restrict__ axh,
                                                unsigned* __restrict__ outU) {
    __shared__ unsigned qq[4][QW][64];     // 39936 B; bank = lane mod 32 (2-way free)

    const int t    = threadIdx.x;
    const int w    = __builtin_amdgcn_readfirstlane(t >> 6);
    const int l    = t & 63;
    const int q31  = l & 31;               // query col (B) AND cand row (A)
    const int hb   = l >> 5;               // half-stream select
    const int qblk = blockIdx.x >> 1;      // 0..511
    const int rp   = blockIdx.x & 1;
    const int range = rp * 4 + w;          // physical 0..7
    const int rbase = range * RLEN;
    const unsigned short* xr  = xh + (size_t)rbase * 64;
    const unsigned short* axr = axh + (size_t)rbase * 8;
    const int q = qblk * 32 + q31;         // lane's own query

    // B-frags: query q, k = s*16 + hb*8 + e, scaled by -2 (exact in bf16)
    s16x8 B0, B1, B2q, B3;
    {
        const unsigned short* qp = xh + (size_t)q * 64 + hb * 8;
        s16x8 h0 = *(const s16x8*)qp;
        s16x8 h1 = *(const s16x8*)(qp + 16);
        s16x8 h2 = *(const s16x8*)(qp + 32);
        s16x8 h3 = *(const s16x8*)(qp + 48);
#pragma unroll
        for (int e = 0; e < 8; ++e) {
            B0[e] = neg2(h0[e]); B1[e] = neg2(h1[e]);
            B2q[e] = neg2(h2[e]); B3[e] = neg2(h3[e]);
        }
    }
    // sq-fold B-frag: B[*][k] = 1.0 for k in {0,1}; k=0..7 live on hb==0 lanes
    s16x8 bs = {0, 0, 0, 0, 0, 0, 0, 0};
    if (hb == 0) { bs[0] = (short)0x3F80; bs[1] = (short)0x3F80; }

    unsigned bd[LC];
#pragma unroll
    for (int k = 0; k < LC; ++k) bd[k] = 0xFFFFFFFFu;
    unsigned tauU = 0xFFFFFFFFu;
    int myq = 0;
    unsigned* myqq = &qq[w][0][l];         // slot i at myqq[i*64]

#define LOADG(F0, F1, F2, F3, Fq, gidx)                                          \
    {                                                                            \
        const unsigned short* ap_ = xr + (size_t)((gidx) * 32 + q31) * 64 + hb * 8; \
        F0 = *(const s16x8*)ap_;                                                 \
        F1 = *(const s16x8*)(ap_ + 16);                                          \
        F2 = *(const s16x8*)(ap_ + 32);                                          \
        F3 = *(const s16x8*)(ap_ + 48);                                          \
        Fq = *(const s16x8*)(axr + (size_t)((gidx) * 32 + q31) * 8);             \
    }

#define PROC(F0, F1, F2, F3, Fq, gidx)                                           \
    {                                                                            \
        f32x16 acc = {0.f};                                                      \
        acc = __builtin_amdgcn_mfma_f32_32x32x16_bf16(F0, B0, acc, 0, 0, 0);     \
        acc = __builtin_amdgcn_mfma_f32_32x32x16_bf16(F1, B1, acc, 0, 0, 0);     \
        acc = __builtin_amdgcn_mfma_f32_32x32x16_bf16(F2, B2q, acc, 0, 0, 0);    \
        acc = __builtin_amdgcn_mfma_f32_32x32x16_bf16(F3, B3, acc, 0, 0, 0);     \
        acc = __builtin_amdgcn_mfma_f32_32x32x16_bf16(Fq, bs, acc, 0, 0, 0);     \
        const unsigned pb_ = (unsigned)((gidx) * 16);                            \
        _Pragma("unroll")                                                        \
        for (int r = 0; r < 16; ++r) {                                           \
            unsigned e_ = (__float_as_uint(acc[r]) & ~1023u) | (pb_ + r);        \
            myqq[myq * 64] = e_;                                                 \
            myq += (e_ < tauU) ? 1 : 0;                                          \
        }                                                                        \
        if (__any(myq > QW - 16)) {                                              \
            for (int i_ = 0; i_ < myq; ++i_) insertU(bd, myqq[i_ * 64]);         \
            myq = 0;                                                             \
            tauU = bd[LC - 1];                                                   \
        }                                                                        \
    }

    // ping-pong: frags for even/odd groups in distinct named registers (no movs)
    s16x8 Pa0, Pa1, Pa2, Pa3, Paq;
    s16x8 Pb0, Pb1, Pb2, Pb3, Pbq;
    LOADG(Pa0, Pa1, Pa2, Pa3, Paq, 0)
    for (int it = 0; it < NCG / 2; ++it) {
        LOADG(Pb0, Pb1, Pb2, Pb3, Pbq, 2 * it + 1)        // prefetch odd group
        PROC (Pa0, Pa1, Pa2, Pa3, Paq, 2 * it)            // compute even group
        LOADG(Pa0, Pa1, Pa2, Pa3, Paq, (2 * it + 2) & 63) // prefetch next even (wraps once, dead)
        PROC (Pb0, Pb1, Pb2, Pb3, Pbq, 2 * it + 1)        // compute odd group
    }
#undef LOADG
#undef PROC

    if (__any(myq != 0)) {
        for (int i = 0; i < myq; ++i) insertU(bd, myqq[i * 64]);
    }

    // write this (virtual-range, query) packed sorted top-10
    const int vr = range * 2 + hb;         // 0..15 virtual ranges
    unsigned* ou = outU + ((size_t)vr * Npts + q) * LC;
#pragma unroll
    for (int k = 0; k < LC; ++k) ou[k] = bd[k];
}

// ------- k_out: 160 packed -> top24 (2-phase rank) -> fp64 top10 -> gather-max -------
__global__ __launch_bounds__(192) void k_out(const float* __restrict__ y,
                                             const float* __restrict__ ptsT,
                                             const unsigned* __restrict__ outU,
                                             float* __restrict__ out) {
    __shared__ unsigned sc[NR * LC];
    __shared__ int    ix[NR * LC];
    __shared__ unsigned s2[96];
    __shared__ int    i2[96];
    __shared__ int    c24[24];
    __shared__ double d2s[24];
    __shared__ int    ci[24];
    __shared__ __align__(16) float qs[Dims];
    __shared__ int    nb[KNN];

    const int n = blockIdx.x;
    const int t = threadIdx.x;

    if (t < Dims) qs[t] = ptsT[(size_t)n * Dims + t];
    if (t < NR * LC) {
        const int rg = t / LC, k = t - rg * LC;   // 160 entries
        unsigned e = outU[((size_t)rg * Npts + n) * LC + k];
        sc[t] = e;
        // decode global candidate index from (vr, packed local idx)
        int lo = (int)(e & 1023u);
        int rr = lo & 15;
        ix[t] = (rg >> 1) * RLEN + (lo >> 4) * 32 + (rr & 3) + 8 * (rr >> 2) + (rg & 1) * 4;
    }
    __syncthreads();

    // phase 1: rank within group of 40, keep top-24 of each (4 groups -> 96)
    if (t < NR * LC) {
        const int gb = (t / 40) * 40;
        const unsigned v = sc[t]; const int vi = ix[t];
        int rk = 0;
        for (int c = 0; c < 40; ++c) {
            unsigned oc = sc[gb + c]; int oi = ix[gb + c];
            rk += (oc < v || (oc == v && oi < vi)) ? 1 : 0;
        }
        if (rk < 24) { s2[(t / 40) * 24 + rk] = v; i2[(t / 40) * 24 + rk] = vi; }
    }
    __syncthreads();

    // phase 2: 96 -> coarse top-24
    if (t < 96) {
        const unsigned v = s2[t]; const int vi = i2[t];
        int rk = 0;
        for (int c = 0; c < 96; ++c)
            rk += (s2[c] < v || (s2[c] == v && i2[c] < vi)) ? 1 : 0;
        if (rk < 24) c24[rk] = vi;
    }
    __syncthreads();

    // exact fp64 d2 for 24 candidates
    if (t < 24) {
        const int j = c24[t];
        double acc = 0.0;
#pragma unroll
        for (int d4 = 0; d4 < Dims / 4; ++d4) {
            const float4 pv = *(const float4*)&ptsT[(size_t)j * Dims + d4 * 4];
            const float4 qv = *(const float4*)&qs[d4 * 4];
            double e0 = (double)qv.x - (double)pv.x;
            double e1 = (double)qv.y - (double)pv.y;
            double e2 = (double)qv.z - (double)pv.z;
            double e3 = (double)qv.w - (double)pv.w;
            acc = fma(e0, e0, acc); acc = fma(e1, e1, acc);
            acc = fma(e2, e2, acc); acc = fma(e3, e3, acc);
        }
        d2s[t] = acc; ci[t] = j;
    }
    __syncthreads();

    // exact top-10 by (d2, idx)
    if (t < 24) {
        const double dv = d2s[t]; const int ji = ci[t];
        int rk = 0;
        for (int c = 0; c < 24; ++c)
            rk += (d2s[c] < dv || (d2s[c] == dv && ci[c] < ji)) ? 1 : 0;
        if (rk < KNN) nb[rk] = ji;
    }
    __syncthreads();

    if (t < Oout) {
        float m = -FLT_MAX;
#pragma unroll
        for (int k = 0; k < KNN; ++k)
            m = fmaxf(m, y[(size_t)nb[k] * Oout + t]);
        out[(size_t)n * Oout + t] = m;
    }
}

// ---------------- launcher ----------------
extern "C" void kernel_launch(void* const* d_in, const int* in_sizes, int n_in,
                              void* d_out, int out_size, void* d_ws, size_t ws_size,
                              hipStream_t stream) {
    const float* x = (const float*)d_in[0];   // (1, 64, 16384)
    const float* W = (const float*)d_in[1];   // (128, 64)
    const float* b = (const float*)d_in[2];   // (128,)
    float* out = (float*)d_out;

    float* ws   = (float*)d_ws;
    float* ptsT = ws;                                        // N*D          (4 MB)
    float* y    = ptsT + (size_t)Npts * Dims;                // N*O          (8 MB)
    unsigned short* xh  = (unsigned short*)(y + (size_t)Npts * Oout); // N*D bf16 (2 MB)
    unsigned short* axh = xh + (size_t)Npts * Dims;          // N*8 bf16     (256 KB)
    unsigned* outU = (unsigned*)(axh + (size_t)Npts * 8);    // NR*N*LC u32  (10.5 MB)

    k_tr <<<Npts / 64, 256, 0, stream>>>(x, ptsT, xh, axh);
    k_y  <<<Npts / 8, 256, 0, stream>>>(ptsT, W, b, y);
    k_knn<<<1024, 256, 0, stream>>>(xh, axh, outU);
    k_out<<<Npts, 192, 0, stream>>>(y, ptsT, outU, out);
}